// Round 8
// baseline (97.440 us; speedup 1.0000x reference)
//
#include <hip/hip_runtime.h>

#define HW 16384   // H*W
#define NH 4
#define HD 16

// ---------------- Kernel 1: QKV projection (LDS-staged x, SGPR weights) ------
__global__ __launch_bounds__(256) void qkv_kernel(
    const float* __restrict__ x, const float* __restrict__ w,
    const float* __restrict__ bias, float* __restrict__ qT,
    float* __restrict__ kT, float* __restrict__ vT)
{
  __shared__ float xs[64][72];
  int slice = blockIdx.x;
  int p0    = blockIdx.y * 64;
  int b     = blockIdx.z;
  int t     = threadIdx.x;

  {
    int c = t >> 2, f4 = t & 3;
    const float4* src = (const float4*)(x + (size_t)(b * 64 + c) * HW + p0);
    float4* dst = (float4*)(&xs[c][0]);
#pragma unroll
    for (int k2 = 0; k2 < 4; ++k2) dst[f4 * 4 + k2] = src[f4 * 4 + k2];
  }
  __syncthreads();

  int px = t & 63;
  int wv  = __builtin_amdgcn_readfirstlane(t >> 6);
  int o16 = slice * 4 + wv;
  int o0  = o16 * 16;
  int tsel = o16 >> 2;
  int h    = o16 & 3;

  float acc[16];
#pragma unroll
  for (int d = 0; d < 16; ++d) acc[d] = bias[o0 + d];

  for (int c4 = 0; c4 < 16; ++c4) {
    float a0 = xs[c4 * 4 + 0][px];
    float a1 = xs[c4 * 4 + 1][px];
    float a2 = xs[c4 * 4 + 2][px];
    float a3 = xs[c4 * 4 + 3][px];
#pragma unroll
    for (int d = 0; d < 16; ++d) {
      const float* wr = w + (o0 + d) * 64 + c4 * 4;
      acc[d] = fmaf(wr[0], a0, acc[d]);
      acc[d] = fmaf(wr[1], a1, acc[d]);
      acc[d] = fmaf(wr[2], a2, acc[d]);
      acc[d] = fmaf(wr[3], a3, acc[d]);
    }
  }
  if (tsel == 0) {
#pragma unroll
    for (int d = 0; d < 16; ++d) acc[d] *= 0.25f;
  }
  float* dst = (tsel == 0) ? qT : ((tsel == 1) ? kT : vT);
  float4* dp = (float4*)(dst + ((size_t)(b * NH + h) * HW + p0 + px) * HD);
  dp[0] = make_float4(acc[0], acc[1], acc[2], acc[3]);
  dp[1] = make_float4(acc[4], acc[5], acc[6], acc[7]);
  dp[2] = make_float4(acc[8], acc[9], acc[10], acc[11]);
  dp[3] = make_float4(acc[12], acc[13], acc[14], acc[15]);
}

// ---------------- Kernel 2: neighborhood attention, reg-pipelined ------------
// grid: dim3(64, 4, 2); block 256 (4 waves). Grid caps CU at 2 blocks = 2
// waves/SIMD, so VGPR<=256 is free: __launch_bounds__(256,2) tells the
// allocator to spend registers on ILP, not phantom occupancy (R7: VGPR=48
// serialized all 98 loads). Half-row (4-key / 3-key) register buffers A/B,
// one-ahead software pipeline: ~12-16 float4 loads always in flight.

// load keys j=0..3 of row ROW into BUF[0..15]
#define LD_H0(BUF, ROW, PTR)                                            \
  { _Pragma("unroll") for (int j = 0; j < 4; ++j)                       \
    { _Pragma("unroll") for (int d4 = 0; d4 < 4; ++d4)                  \
      BUF[j * 4 + d4] = ((const float4*)((PTR) + (ROW) * 2048 + j * HD))[d4]; } }
// load keys j=4..6 of row ROW into BUF[0..11]
#define LD_H1(BUF, ROW, PTR)                                            \
  { _Pragma("unroll") for (int j = 4; j < 7; ++j)                       \
    { _Pragma("unroll") for (int d4 = 0; d4 < 4; ++d4)                  \
      BUF[(j - 4) * 4 + d4] = ((const float4*)((PTR) + (ROW) * 2048 + j * HD))[d4]; } }

#define QK_KEY(BUF, K0, ROW, J)                                         \
  { float dd = rbl[(ih + (ROW)) * 13 + iw + (J)];                       \
    float4 k0 = BUF[(K0) + 0], k1 = BUF[(K0) + 1],                      \
           k2 = BUF[(K0) + 2], k3 = BUF[(K0) + 3];                      \
    dd = fmaf(qd[0], k0.x, dd);  dd = fmaf(qd[1], k0.y, dd);            \
    dd = fmaf(qd[2], k0.z, dd);  dd = fmaf(qd[3], k0.w, dd);            \
    dd = fmaf(qd[4], k1.x, dd);  dd = fmaf(qd[5], k1.y, dd);            \
    dd = fmaf(qd[6], k1.z, dd);  dd = fmaf(qd[7], k1.w, dd);            \
    dd = fmaf(qd[8], k2.x, dd);  dd = fmaf(qd[9], k2.y, dd);            \
    dd = fmaf(qd[10], k2.z, dd); dd = fmaf(qd[11], k2.w, dd);           \
    dd = fmaf(qd[12], k3.x, dd); dd = fmaf(qd[13], k3.y, dd);           \
    dd = fmaf(qd[14], k3.z, dd); dd = fmaf(qd[15], k3.w, dd);           \
    lg[(ROW) * 7 + (J)] = dd; }

#define QK_H0(BUF, ROW)                                                 \
  QK_KEY(BUF, 0, ROW, 0) QK_KEY(BUF, 4, ROW, 1)                         \
  QK_KEY(BUF, 8, ROW, 2) QK_KEY(BUF, 12, ROW, 3)
#define QK_H1(BUF, ROW)                                                 \
  QK_KEY(BUF, 0, ROW, 4) QK_KEY(BUF, 4, ROW, 5) QK_KEY(BUF, 8, ROW, 6)

#define PV_KEY(BUF, K0, ROW, J)                                         \
  { float p = lg[(ROW) * 7 + (J)];                                      \
    float4 v0 = BUF[(K0) + 0], v1 = BUF[(K0) + 1],                      \
           v2 = BUF[(K0) + 2], v3 = BUF[(K0) + 3];                      \
    o[0] = fmaf(p, v0.x, o[0]);   o[1] = fmaf(p, v0.y, o[1]);           \
    o[2] = fmaf(p, v0.z, o[2]);   o[3] = fmaf(p, v0.w, o[3]);           \
    o[4] = fmaf(p, v1.x, o[4]);   o[5] = fmaf(p, v1.y, o[5]);           \
    o[6] = fmaf(p, v1.z, o[6]);   o[7] = fmaf(p, v1.w, o[7]);           \
    o[8] = fmaf(p, v2.x, o[8]);   o[9] = fmaf(p, v2.y, o[9]);           \
    o[10] = fmaf(p, v2.z, o[10]); o[11] = fmaf(p, v2.w, o[11]);         \
    o[12] = fmaf(p, v3.x, o[12]); o[13] = fmaf(p, v3.y, o[13]);         \
    o[14] = fmaf(p, v3.z, o[14]); o[15] = fmaf(p, v3.w, o[15]); }

#define PV_H0(BUF, ROW)                                                 \
  PV_KEY(BUF, 0, ROW, 0) PV_KEY(BUF, 4, ROW, 1)                         \
  PV_KEY(BUF, 8, ROW, 2) PV_KEY(BUF, 12, ROW, 3)
#define PV_H1(BUF, ROW)                                                 \
  PV_KEY(BUF, 0, ROW, 4) PV_KEY(BUF, 4, ROW, 5) PV_KEY(BUF, 8, ROW, 6)

__global__ __launch_bounds__(256, 2) void attn_kernel(
    const float* __restrict__ qT, const float* __restrict__ kT,
    const float* __restrict__ vT, const float* __restrict__ rb,
    float* __restrict__ attO)
{
  __shared__ float rbl[169];

  int t   = threadIdx.x;
  int h   = blockIdx.y;
  int b   = blockIdx.z;
  int n   = blockIdx.x * 256 + t;
  int y   = n >> 7, xc = n & 127;
  int sy  = y - 3;  sy = sy < 0 ? 0 : (sy > 121 ? 121 : sy);
  int sx  = xc - 3; sx = sx < 0 ? 0 : (sx > 121 ? 121 : sx);
  int ih  = y - sy, iw = xc - sx;

  size_t base = (size_t)(b * NH + h) * HW;

  // stage bias first; barrier BEFORE prefetch (syncthreads drains vmcnt)
  if (t < 169) rbl[t] = rb[t * NH + h];
  __syncthreads();

  float qd[16];
  {
    const float4* qp = (const float4*)(qT + (base + n) * HD);
#pragma unroll
    for (int k = 0; k < 4; ++k) {
      float4 v = qp[k];
      qd[4 * k + 0] = v.x; qd[4 * k + 1] = v.y;
      qd[4 * k + 2] = v.z; qd[4 * k + 3] = v.w;
    }
  }

  const float* kwin = kT + (base + (size_t)sy * 128 + sx) * HD;
  const float* vwin = vT + (base + (size_t)sy * 128 + sx) * HD;

  float lg[49];
  float4 A[16], B[16];

  // ---- pass 1: QK^T, one-half-row-ahead pipeline ----
  LD_H0(A, 0, kwin) LD_H1(B, 0, kwin)
  QK_H0(A, 0) LD_H0(A, 1, kwin)
  QK_H1(B, 0) LD_H1(B, 1, kwin)
  QK_H0(A, 1) LD_H0(A, 2, kwin)
  QK_H1(B, 1) LD_H1(B, 2, kwin)
  QK_H0(A, 2) LD_H0(A, 3, kwin)
  QK_H1(B, 2) LD_H1(B, 3, kwin)
  QK_H0(A, 3) LD_H0(A, 4, kwin)
  QK_H1(B, 3) LD_H1(B, 4, kwin)
  QK_H0(A, 4) LD_H0(A, 5, kwin)
  QK_H1(B, 4) LD_H1(B, 5, kwin)
  QK_H0(A, 5) LD_H0(A, 6, kwin)
  QK_H1(B, 5) LD_H1(B, 6, kwin)
  QK_H0(A, 6)
  QK_H1(B, 6)

  // ---- prefetch V row 0 (first half) under the softmax ----
  LD_H0(A, 0, vwin)

  // ---- softmax ----
  float mx = lg[0];
#pragma unroll
  for (int k = 1; k < 49; ++k) mx = fmaxf(mx, lg[k]);
  float s = 0.f;
#pragma unroll
  for (int k = 0; k < 49; ++k) { lg[k] = __expf(lg[k] - mx); s += lg[k]; }
  float inv = 1.f / s;

  // ---- pass 2: PV, same pipeline ----
  float o[16];
#pragma unroll
  for (int d = 0; d < 16; ++d) o[d] = 0.f;

  LD_H1(B, 0, vwin)
  PV_H0(A, 0) LD_H0(A, 1, vwin)
  PV_H1(B, 0) LD_H1(B, 1, vwin)
  PV_H0(A, 1) LD_H0(A, 2, vwin)
  PV_H1(B, 1) LD_H1(B, 2, vwin)
  PV_H0(A, 2) LD_H0(A, 3, vwin)
  PV_H1(B, 2) LD_H1(B, 3, vwin)
  PV_H0(A, 3) LD_H0(A, 4, vwin)
  PV_H1(B, 3) LD_H1(B, 4, vwin)
  PV_H0(A, 4) LD_H0(A, 5, vwin)
  PV_H1(B, 4) LD_H1(B, 5, vwin)
  PV_H0(A, 5) LD_H0(A, 6, vwin)
  PV_H1(B, 5) LD_H1(B, 6, vwin)
  PV_H0(A, 6)
  PV_H1(B, 6)

  // write channel-major (pre-projection) into attO (= d_out, overwritten later)
  float* ob = attO + (size_t)b * 64 * HW + (size_t)h * 16 * HW + n;
#pragma unroll
  for (int d = 0; d < 16; ++d) ob[d * HW] = o[d] * inv;
}

// ---------------- Kernel 3: output projection (in-place over d_out) ----------
__global__ __launch_bounds__(256) void proj_kernel(
    const float* __restrict__ pw, const float* __restrict__ pb,
    float* __restrict__ out)
{
  __shared__ float as[64][72];
  int p0 = blockIdx.x * 64;
  int b  = blockIdx.y;
  int t  = threadIdx.x;

  {
    int c = t >> 2, f4 = t & 3;
    const float4* src = (const float4*)(out + (size_t)(b * 64 + c) * HW + p0);
    float4* dst = (float4*)(&as[c][0]);
#pragma unroll
    for (int k2 = 0; k2 < 4; ++k2) dst[f4 * 4 + k2] = src[f4 * 4 + k2];
  }
  __syncthreads();

  int px = t & 63;
  int og = __builtin_amdgcn_readfirstlane(t >> 6);
  float acc[16];
#pragma unroll
  for (int oo = 0; oo < 16; ++oo) acc[oo] = pb[og * 16 + oo];

  for (int c4 = 0; c4 < 16; ++c4) {
    float a0 = as[c4 * 4 + 0][px];
    float a1 = as[c4 * 4 + 1][px];
    float a2 = as[c4 * 4 + 2][px];
    float a3 = as[c4 * 4 + 3][px];
#pragma unroll
    for (int oo = 0; oo < 16; ++oo) {
      const float* wr = pw + (og * 16 + oo) * 64 + c4 * 4;
      acc[oo] = fmaf(wr[0], a0, acc[oo]);
      acc[oo] = fmaf(wr[1], a1, acc[oo]);
      acc[oo] = fmaf(wr[2], a2, acc[oo]);
      acc[oo] = fmaf(wr[3], a3, acc[oo]);
    }
  }
#pragma unroll
  for (int oo = 0; oo < 16; ++oo)
    out[((size_t)b * 64 + og * 16 + oo) * HW + p0 + px] = acc[oo];
}

extern "C" void kernel_launch(void* const* d_in, const int* in_sizes, int n_in,
                              void* d_out, int out_size, void* d_ws, size_t ws_size,
                              hipStream_t stream) {
  const float* x      = (const float*)d_in[0];
  const float* qkv_w  = (const float*)d_in[1];
  const float* qkv_b  = (const float*)d_in[2];
  const float* proj_w = (const float*)d_in[3];
  const float* proj_b = (const float*)d_in[4];
  const float* rb     = (const float*)d_in[5];
  float* out = (float*)d_out;

  const size_t TSZ = (size_t)2 * NH * HW * HD;   // 2,097,152 floats each
  float* qT = (float*)d_ws;
  float* kT = qT + TSZ;
  float* vT = kT + TSZ;

  qkv_kernel<<<dim3(3, 256, 2), 256, 0, stream>>>(x, qkv_w, qkv_b, qT, kT, vT);
  attn_kernel<<<dim3(64, NH, 2), 256, 0, stream>>>(qT, kT, vT, rb, out);
  proj_kernel<<<dim3(256, 2), 256, 0, stream>>>(proj_w, proj_b, out);
}